// Round 12
// baseline (192.567 us; speedup 1.0000x reference)
//
#include <hip/hip_runtime.h>

// VQ-VAE quantization, round 12: shared-B GEMM structure.
// Diagnosis r2-r11: per-CU throughput pinned at ~280 cyc/body by L1/L2 line
// traffic — each wave privately pulled 2.3KB per 16-code body. Fix: block =
// 4 waves x 32 points = 128 points; all waves sweep ALL codes in lockstep
// over a double-buffered LDS B-tile (32 codes, 4KB) staged once per block
// via global_load_lds -> per-CU codebook bytes drop ~4x.
// cbb is PRE-TILED by vq_prep: [tile][dim-group g][code][8 bf16] so staging
// is linear and ds_read_b128 fragments are stride-16B = conflict-free.
// Threshold: per-wave sampled max (16 of 128 tiles) - DELTA; provably safe
// (s(c*) >= sampledmax - 2*eps, DELTA=0.25 >= 2*eps). Exact fp32 rescore +
// LDS atomicMin((ordbits(dist)<<32)|code) -> exact argmin, first-index ties.

#define NPTS    65536
#define CDIM    64
#define KCODES  4096
#define PPB     128                 // points per block
#define NT      (KCODES / 32)       // 128 tiles of 32 codes
#define NSAMP   16                  // sample tiles (stride 8)
#define LISTCAP 6144
#define DELTA   0.25f

typedef __attribute__((ext_vector_type(8))) short short8;
typedef __attribute__((ext_vector_type(4))) float f32x4;

__device__ __forceinline__ unsigned short f2bf(float x) {
    unsigned u = __float_as_uint(x);
    return (unsigned short)((u + 0x7FFFu + ((u >> 16) & 1u)) >> 16);  // RNE
}

// cb fp32 -> tiled bf16 codebook + h[k] = 0.5*||e_k||^2.
// Tile layout: chunk T (4096B) = [g=0..7][code cc=0..31][8 bf16 dims]:
//   byte offset = T*4096 + g*512 + cc*16, dims [g*8, g*8+8).
__global__ __launch_bounds__(256) void vq_prep(const float* __restrict__ cb,
                                               char* __restrict__ cbb,
                                               float* __restrict__ h) {
    int c = blockIdx.x * 256 + threadIdx.x;
    int T = c >> 5, cc = c & 31;
    const float4* p = reinterpret_cast<const float4*>(cb + (size_t)c * CDIM);
    float s0 = 0.f, s1 = 0.f, s2 = 0.f, s3 = 0.f;
#pragma unroll
    for (int g = 0; g < 8; ++g) {
        float4 va = p[2 * g], vb = p[2 * g + 1];
        s0 = fmaf(va.x, va.x, s0); s1 = fmaf(va.y, va.y, s1);
        s2 = fmaf(va.z, va.z, s2); s3 = fmaf(va.w, va.w, s3);
        s0 = fmaf(vb.x, vb.x, s0); s1 = fmaf(vb.y, vb.y, s1);
        s2 = fmaf(vb.z, vb.z, s2); s3 = fmaf(vb.w, vb.w, s3);
        short8 o;
        o[0] = (short)f2bf(va.x); o[1] = (short)f2bf(va.y);
        o[2] = (short)f2bf(va.z); o[3] = (short)f2bf(va.w);
        o[4] = (short)f2bf(vb.x); o[5] = (short)f2bf(vb.y);
        o[6] = (short)f2bf(vb.z); o[7] = (short)f2bf(vb.w);
        *reinterpret_cast<short8*>(cbb + (size_t)T * 4096 + g * 512 + cc * 16) = o;
    }
    h[c] = 0.5f * ((s0 + s1) + (s2 + s3));
}

__global__ __launch_bounds__(256) void vq_main(const float* __restrict__ enc,
                                               const float* __restrict__ cbf,
                                               const char* __restrict__ cbb,
                                               const float* __restrict__ h,
                                               float* __restrict__ out) {
    __shared__ char bstage[2][4096];
    __shared__ float hstage[2][32];
    __shared__ unsigned list[LISTCAP];
    __shared__ unsigned long long mkey[PPB];
    __shared__ unsigned lcnt;

    const int tid  = threadIdx.x;
    const int wid  = tid >> 6, lane = tid & 63;
    const int lrow = lane & 15, lseg = lane >> 4;
    const int pbase = blockIdx.x * PPB;

    if (tid == 0) lcnt = 0;
    if (tid < PPB) mkey[tid] = ~0ull;

    // ---- A fragments: this wave's 32 points (rows wid*32 + rt*16 + lrow) ----
    // 16x16x32 A layout: row = lane&15, k = (lane>>4)*8 + e (+32 per kk)
    short8 afr[2][2];
#pragma unroll
    for (int rt = 0; rt < 2; ++rt)
#pragma unroll
        for (int kk = 0; kk < 2; ++kk) {
            const float4* xp = reinterpret_cast<const float4*>(
                enc + (size_t)(pbase + wid * 32 + rt * 16 + lrow) * CDIM + kk * 32 + lseg * 8);
            float4 v0 = xp[0], v1 = xp[1];
            short8 a;
            a[0] = (short)f2bf(v0.x); a[1] = (short)f2bf(v0.y);
            a[2] = (short)f2bf(v0.z); a[3] = (short)f2bf(v0.w);
            a[4] = (short)f2bf(v1.x); a[5] = (short)f2bf(v1.y);
            a[6] = (short)f2bf(v1.z); a[7] = (short)f2bf(v1.w);
            afr[rt][kk] = a;
        }

    // Stage tile T into buf: 4KB linear via global_load_lds (each wave covers
    // its 1KB quarter: dest base wave-uniform, lane offset = lane*16 by HW).
    auto stageT = [&](int T, int buf) {
        const char* g = cbb + ((size_t)T << 12) + (unsigned)tid * 16;
        __builtin_amdgcn_global_load_lds(
            (const __attribute__((address_space(1))) unsigned*)g,
            (__attribute__((address_space(3))) unsigned*)(&bstage[buf][wid * 1024]), 16, 0, 0);
        if (tid < 32) hstage[buf][tid] = h[T * 32 + tid];
    };

    const unsigned vb = (unsigned)(lseg * 512 + lrow * 16);

    // compute tile in buf -> acc0 (codes lrow), acc1 (codes 16+lrow), minus h
    auto computeT = [&](int buf, f32x4* acc0, f32x4* acc1) {
        const char* bb2 = &bstage[buf][0];
        short8 b00 = *reinterpret_cast<const short8*>(bb2 + vb);           // s0,kk0
        short8 b01 = *reinterpret_cast<const short8*>(bb2 + vb + 2048);    // s0,kk1
        short8 b10 = *reinterpret_cast<const short8*>(bb2 + vb + 256);     // s1,kk0
        short8 b11 = *reinterpret_cast<const short8*>(bb2 + vb + 2304);    // s1,kk1
        float nh0 = -hstage[buf][lrow];
        float nh1 = -hstage[buf][16 + lrow];
#pragma unroll
        for (int rt = 0; rt < 2; ++rt) {
            acc0[rt][0] = nh0; acc0[rt][1] = nh0; acc0[rt][2] = nh0; acc0[rt][3] = nh0;
            acc1[rt][0] = nh1; acc1[rt][1] = nh1; acc1[rt][2] = nh1; acc1[rt][3] = nh1;
        }
#pragma unroll
        for (int rt = 0; rt < 2; ++rt) {
            acc0[rt] = __builtin_amdgcn_mfma_f32_16x16x32_bf16(afr[rt][0], b00, acc0[rt], 0, 0, 0);
            acc1[rt] = __builtin_amdgcn_mfma_f32_16x16x32_bf16(afr[rt][0], b10, acc1[rt], 0, 0, 0);
        }
#pragma unroll
        for (int rt = 0; rt < 2; ++rt) {
            acc0[rt] = __builtin_amdgcn_mfma_f32_16x16x32_bf16(afr[rt][1], b01, acc0[rt], 0, 0, 0);
            acc1[rt] = __builtin_amdgcn_mfma_f32_16x16x32_bf16(afr[rt][1], b11, acc1[rt], 0, 0, 0);
        }
    };

    // ---- sample sweep: tiles {0,8,...,120} -> per-wave row max ----
    f32x4 best0[2], best1[2];
#pragma unroll
    for (int rt = 0; rt < 2; ++rt)
#pragma unroll
        for (int i = 0; i < 4; ++i) { best0[rt][i] = -__builtin_inff(); best1[rt][i] = -__builtin_inff(); }

    int buf = 0;
    stageT(0, 0);
    __syncthreads();
    for (int j = 0; j < NSAMP; ++j) {
        if (j + 1 < NSAMP) stageT((j + 1) * 8, buf ^ 1);
        f32x4 a0[2], a1[2];
        computeT(buf, a0, a1);
#pragma unroll
        for (int rt = 0; rt < 2; ++rt)
#pragma unroll
            for (int i = 0; i < 4; ++i) {
                best0[rt][i] = fmaxf(best0[rt][i], a0[rt][i]);
                best1[rt][i] = fmaxf(best1[rt][i], a1[rt][i]);
            }
        __syncthreads();
        buf ^= 1;
    }

    // per-row threshold: max over 16 col-lanes of max(best0,best1), - DELTA
    f32x4 thr[2];
#pragma unroll
    for (int rt = 0; rt < 2; ++rt)
#pragma unroll
        for (int i = 0; i < 4; ++i) thr[rt][i] = fmaxf(best0[rt][i], best1[rt][i]);
#pragma unroll
    for (int m = 1; m <= 8; m <<= 1)
#pragma unroll
        for (int rt = 0; rt < 2; ++rt)
#pragma unroll
            for (int i = 0; i < 4; ++i)
                thr[rt][i] = fmaxf(thr[rt][i], __shfl_xor(thr[rt][i], m, 64));
#pragma unroll
    for (int rt = 0; rt < 2; ++rt)
#pragma unroll
        for (int i = 0; i < 4; ++i) thr[rt][i] -= DELTA;

    // ---- main sweep: all 128 tiles; ballot-gated push ----
    stageT(0, buf);
    __syncthreads();
    for (int j = 0; j < NT; ++j) {
        if (j + 1 < NT) stageT(j + 1, buf ^ 1);
        f32x4 a0[2], a1[2];
        computeT(buf, a0, a1);
        f32x4 d0[2], d1[2];
#pragma unroll
        for (int rt = 0; rt < 2; ++rt)
#pragma unroll
            for (int i = 0; i < 4; ++i) {
                d0[rt][i] = a0[rt][i] - thr[rt][i];
                d1[rt][i] = a1[rt][i] - thr[rt][i];
            }
        float g0 = fmaxf(fmaxf(fmaxf(d0[0][0], d0[0][1]), fmaxf(d0[0][2], d0[0][3])),
                         fmaxf(fmaxf(d0[1][0], d0[1][1]), fmaxf(d0[1][2], d0[1][3])));
        float g1 = fmaxf(fmaxf(fmaxf(d1[0][0], d1[0][1]), fmaxf(d1[0][2], d1[0][3])),
                         fmaxf(fmaxf(d1[1][0], d1[1][1]), fmaxf(d1[1][2], d1[1][3])));
        if (__ballot(fmaxf(g0, g1) >= 0.f)) {
            unsigned c0 = (unsigned)(j * 32 + lrow);
#pragma unroll
            for (int rt = 0; rt < 2; ++rt)
#pragma unroll
                for (int i = 0; i < 4; ++i) {
                    unsigned row = (unsigned)(wid * 32 + rt * 16 + lseg * 4 + i);  // C/D map (m89)
                    if (d0[rt][i] >= 0.f) {
                        unsigned pos = atomicAdd(&lcnt, 1u);
                        if (pos < LISTCAP) list[pos] = (row << 12) | c0;
                    }
                    if (d1[rt][i] >= 0.f) {
                        unsigned pos = atomicAdd(&lcnt, 1u);
                        if (pos < LISTCAP) list[pos] = (row << 12) | (c0 + 16);
                    }
                }
        }
        __syncthreads();
        buf ^= 1;
    }

    // ---- exact fp32 rescore: 4 lanes per candidate (coalesced 256B) ----
    unsigned cnt = lcnt; if (cnt > LISTCAP) cnt = LISTCAP;
    for (unsigned t4 = tid; t4 < cnt * 4; t4 += 256) {
        unsigned t = t4 >> 2; int q = t4 & 3;
        unsigned e = list[t];
        int row = (int)(e >> 12), c = (int)(e & 4095u);
        const float4* xp = reinterpret_cast<const float4*>(enc + (size_t)(pbase + row) * CDIM) + q * 4;
        const float4* ep = reinterpret_cast<const float4*>(cbf + (size_t)c * CDIM) + q * 4;
        float a0 = 0.f, a1 = 0.f, a2 = 0.f, a3 = 0.f;
#pragma unroll
        for (int i = 0; i < 4; ++i) {
            float4 xv = xp[i], ev = ep[i];
            a0 = fmaf(xv.x, ev.x, a0); a1 = fmaf(xv.y, ev.y, a1);
            a2 = fmaf(xv.z, ev.z, a2); a3 = fmaf(xv.w, ev.w, a3);
        }
        float p = (a0 + a1) + (a2 + a3);
        p += __shfl_xor(p, 1, 64);
        p += __shfl_xor(p, 2, 64);               // full dot in all 4 lanes
        if (q == 0) {
            float d2 = fmaf(-2.f, p, 2.f * h[c]);     // esq - 2*dot (bit-identical everywhere)
            unsigned bb = __float_as_uint(d2);
            unsigned ord = bb ^ (unsigned)(((int)bb >> 31) | 0x80000000);  // monotonic
            atomicMin(&mkey[row], ((unsigned long long)ord << 32) | (unsigned)c);
        }
    }
    __syncthreads();

    // ---- finalize: gather winner rows (2 threads per point) + idx ----
    {
        int p = tid >> 1, half = tid & 1;
        int c = (int)(mkey[p] & 4095u);
        const float4* ep = reinterpret_cast<const float4*>(cbf + (size_t)c * CDIM) + half * 8;
        float4* op = reinterpret_cast<float4*>(out + (size_t)(pbase + p) * CDIM) + half * 8;
#pragma unroll
        for (int i = 0; i < 8; ++i) op[i] = ep[i];
        if (tid < PPB)
            out[(size_t)NPTS * CDIM + pbase + tid] = (float)(mkey[tid] & 4095u);
    }
}

extern "C" void kernel_launch(void* const* d_in, const int* in_sizes, int n_in,
                              void* d_out, int out_size, void* d_ws, size_t ws_size,
                              hipStream_t stream) {
    const float* enc = (const float*)d_in[0];
    const float* cb  = (const float*)d_in[1];
    float* out = (float*)d_out;

    // ws: cbb tiled bf16 (512KB) | h fp32[4096] (16KB)
    char*  cbb = (char*)d_ws;
    float* hws = (float*)(cbb + (size_t)KCODES * CDIM * 2);

    vq_prep<<<KCODES / 256, 256, 0, stream>>>(cb, cbb, hws);
    vq_main<<<NPTS / PPB, 256, 0, stream>>>(enc, cb, cbb, hws, out);
}

// Round 15
// 135.346 us; speedup vs baseline: 1.4228x; 1.4228x over previous
//
#include <hip/hip_runtime.h>

// VQ-VAE quantization, round 15: bf16 MFMA prefilter + exact fp32 rescore.
// r11 base (155us) with the push machinery rebuilt:
//  - sweep2 acc C-init = -h - thr  -> push test is sign(acc)
//  - per-lane 16-bit candidate mask (cndmask/or), then while(mask){ctz; push}
//    -> replaces 16 exec-mask push regions + 15-fmax tree + ballot (the ~94%
//    dirty-tile overhead that inflated VALU 2-4x).
// Sampled threshold (8/64 tiles/wave + cross-wave max) - DELTA=0.25 (>= 2x
// worst bf16 dot err) provably keeps the true winner; exact fp32 rescore +
// LDS atomicMin((ordbits(dist)<<32)|code) -> exact argmin, first-index ties.

#define NPTS    65536
#define CDIM    64
#define KCODES  4096
#define WAVES   4
#define KPW     (KCODES / WAVES)   // 1024 codes per wave
#define TILES   (KPW / 16)         // 64 tiles of 16 codes
#define LISTCAP 8192
#define DELTA   0.25f

typedef __attribute__((ext_vector_type(8))) short short8;
typedef __attribute__((ext_vector_type(4))) float f32x4;

__device__ __forceinline__ unsigned short f2bf(float x) {
    unsigned u = __float_as_uint(x);
    return (unsigned short)((u + 0x7FFFu + ((u >> 16) & 1u)) >> 16);  // RNE
}

struct BT { short8 b0, b1; float hh; };

// cb fp32 -> bf16 copy + h[k] = 0.5*||e_k||^2
__global__ __launch_bounds__(256) void vq_prep(const float* __restrict__ cb,
                                               short* __restrict__ cbb,
                                               float* __restrict__ h) {
    int k = blockIdx.x * 256 + threadIdx.x;
    const float4* p = reinterpret_cast<const float4*>(cb + (size_t)k * CDIM);
    float s0 = 0.f, s1 = 0.f, s2 = 0.f, s3 = 0.f;
#pragma unroll
    for (int i = 0; i < 16; i += 2) {
        float4 va = p[i], vb = p[i + 1];
        s0 = fmaf(va.x, va.x, s0); s1 = fmaf(va.y, va.y, s1);
        s2 = fmaf(va.z, va.z, s2); s3 = fmaf(va.w, va.w, s3);
        s0 = fmaf(vb.x, vb.x, s0); s1 = fmaf(vb.y, vb.y, s1);
        s2 = fmaf(vb.z, vb.z, s2); s3 = fmaf(vb.w, vb.w, s3);
        short8 o;
        o[0] = (short)f2bf(va.x); o[1] = (short)f2bf(va.y);
        o[2] = (short)f2bf(va.z); o[3] = (short)f2bf(va.w);
        o[4] = (short)f2bf(vb.x); o[5] = (short)f2bf(vb.y);
        o[6] = (short)f2bf(vb.z); o[7] = (short)f2bf(vb.w);
        *reinterpret_cast<short8*>(cbb + (size_t)k * CDIM + i * 4) = o;
    }
    h[k] = 0.5f * ((s0 + s1) + (s2 + s3));
}

__global__ __launch_bounds__(256) void vq_main(const float* __restrict__ enc,
                                               const float* __restrict__ cbf,
                                               const short* __restrict__ cbb,
                                               const float* __restrict__ h,
                                               float* __restrict__ out) {
    __shared__ unsigned list[LISTCAP];
    __shared__ float rowmax[WAVES][64];
    __shared__ float thrL[64];
    __shared__ unsigned long long mkey[64];
    __shared__ unsigned lcnt;

    const int tid  = threadIdx.x;
    const int wid  = tid >> 6, lane = tid & 63;
    const int lrow = lane & 15, lseg = lane >> 4;
    const int pbase = blockIdx.x * 64;     // 64 points per block
    const int k0 = wid * KPW;              // this wave's 1024-code slice

    if (tid == 0) lcnt = 0;
    if (tid < 64) mkey[tid] = ~0ull;

    // ---- A fragments: the block's 64 points as bf16 ----
    // 16x16x32 A layout: row = lane&15, k = (lane>>4)*8 + e (+32 per kk)
    short8 afr[4][2];
#pragma unroll
    for (int rt = 0; rt < 4; ++rt)
#pragma unroll
        for (int kk = 0; kk < 2; ++kk) {
            const float4* xp = reinterpret_cast<const float4*>(
                enc + (size_t)(pbase + rt * 16 + lrow) * CDIM + kk * 32 + lseg * 8);
            float4 v0 = xp[0], v1 = xp[1];
            short8 a;
            a[0] = (short)f2bf(v0.x); a[1] = (short)f2bf(v0.y);
            a[2] = (short)f2bf(v0.z); a[3] = (short)f2bf(v0.w);
            a[4] = (short)f2bf(v1.x); a[5] = (short)f2bf(v1.y);
            a[6] = (short)f2bf(v1.z); a[7] = (short)f2bf(v1.w);
            afr[rt][kk] = a;
        }
    __syncthreads();   // lcnt/mkey init visible before any push

    auto loadB = [&](int ct, BT& s) {
        int code = k0 + ct * 16 + lrow;
        const short* base = cbb + (size_t)code * CDIM + lseg * 8;
        s.b0 = *reinterpret_cast<const short8*>(base);
        s.b1 = *reinterpret_cast<const short8*>(base + 32);
        s.hh = h[code];
    };

    // ---- sample sweep: tiles {0,8,...,56}, row max only ----
    f32x4 best[4];
#pragma unroll
    for (int rt = 0; rt < 4; ++rt)
#pragma unroll
        for (int i = 0; i < 4; ++i) best[rt][i] = -__builtin_inff();

    {
        BT s0, s1, s2, s3;
        loadB(0, s0); loadB(8, s1); loadB(16, s2); loadB(24, s3);
#define SSBODY(SLOT, J)                                                        \
        {                                                                      \
            float nh = -SLOT.hh;                                               \
            f32x4 acc[4];                                                      \
            _Pragma("unroll")                                                  \
            for (int rt = 0; rt < 4; ++rt) {                                   \
                acc[rt][0] = nh; acc[rt][1] = nh;                              \
                acc[rt][2] = nh; acc[rt][3] = nh;                              \
            }                                                                  \
            _Pragma("unroll")                                                  \
            for (int rt = 0; rt < 4; ++rt)                                     \
                acc[rt] = __builtin_amdgcn_mfma_f32_16x16x32_bf16(afr[rt][0], SLOT.b0, acc[rt], 0, 0, 0); \
            _Pragma("unroll")                                                  \
            for (int rt = 0; rt < 4; ++rt)                                     \
                acc[rt] = __builtin_amdgcn_mfma_f32_16x16x32_bf16(afr[rt][1], SLOT.b1, acc[rt], 0, 0, 0); \
            _Pragma("unroll")                                                  \
            for (int rt = 0; rt < 4; ++rt)                                     \
                _Pragma("unroll")                                              \
                for (int i = 0; i < 4; ++i)                                    \
                    best[rt][i] = fmaxf(best[rt][i], acc[rt][i]);              \
            loadB((((J) + 4) & 7) * 8, SLOT);                                  \
        }
        SSBODY(s0, 0) SSBODY(s1, 1) SSBODY(s2, 2) SSBODY(s3, 3)
        SSBODY(s0, 4) SSBODY(s1, 5) SSBODY(s2, 6) SSBODY(s3, 7)
#undef SSBODY
    }

    // intra-wave max over the 16 col-lanes
#pragma unroll
    for (int m = 1; m <= 8; m <<= 1)
#pragma unroll
        for (int rt = 0; rt < 4; ++rt)
#pragma unroll
            for (int i = 0; i < 4; ++i)
                best[rt][i] = fmaxf(best[rt][i], __shfl_xor(best[rt][i], m, 64));
    if (lrow == 0) {   // lanes 0,16,32,48 cover all 64 rows
#pragma unroll
        for (int rt = 0; rt < 4; ++rt)
#pragma unroll
            for (int i = 0; i < 4; ++i)
                rowmax[wid][rt * 16 + lseg * 4 + i] = best[rt][i];
    }
    __syncthreads();
    if (tid < 64) {    // cross-wave max of sampled maxes -> threshold
        float m0 = fmaxf(rowmax[0][tid], rowmax[1][tid]);
        float m1 = fmaxf(rowmax[2][tid], rowmax[3][tid]);
        thrL[tid] = fmaxf(m0, m1) - DELTA;
    }
    __syncthreads();

    f32x4 thr[4];
#pragma unroll
    for (int rt = 0; rt < 4; ++rt)
#pragma unroll
        for (int i = 0; i < 4; ++i) thr[rt][i] = thrL[rt * 16 + lseg * 4 + i];

    // ---- sweep 2: C-init = -h - thr; sign-bit mask + ctz push loop ----
    {
        BT s0, s1, s2, s3;
        loadB(0, s0); loadB(1, s1); loadB(2, s2); loadB(3, s3);
#define S2BODY(SLOT, T)                                                        \
        {                                                                      \
            float nh = -SLOT.hh;                                               \
            f32x4 acc[4];                                                      \
            _Pragma("unroll")                                                  \
            for (int rt = 0; rt < 4; ++rt)                                     \
                _Pragma("unroll")                                              \
                for (int i = 0; i < 4; ++i)                                    \
                    acc[rt][i] = nh - thr[rt][i];                              \
            _Pragma("unroll")                                                  \
            for (int rt = 0; rt < 4; ++rt)                                     \
                acc[rt] = __builtin_amdgcn_mfma_f32_16x16x32_bf16(afr[rt][0], SLOT.b0, acc[rt], 0, 0, 0); \
            _Pragma("unroll")                                                  \
            for (int rt = 0; rt < 4; ++rt)                                     \
                acc[rt] = __builtin_amdgcn_mfma_f32_16x16x32_bf16(afr[rt][1], SLOT.b1, acc[rt], 0, 0, 0); \
            unsigned mask = 0u;                                                \
            _Pragma("unroll")                                                  \
            for (int rt = 0; rt < 4; ++rt)                                     \
                _Pragma("unroll")                                              \
                for (int i = 0; i < 4; ++i)                                    \
                    mask |= (acc[rt][i] >= 0.f) ? (1u << (rt * 4 + i)) : 0u;   \
            if (mask) {                                                        \
                unsigned code = (unsigned)(k0 + (T) * 16 + lrow);              \
                do {                                                           \
                    int kz = __builtin_ctz(mask);                              \
                    mask &= mask - 1u;                                         \
                    unsigned row = ((unsigned)(kz >> 2) << 4)                  \
                                 + (unsigned)(lseg * 4) + (unsigned)(kz & 3);  /* C/D map (m89) */ \
                    unsigned pos = atomicAdd(&lcnt, 1u);                       \
                    if (pos < LISTCAP) list[pos] = (row << 12) | code;         \
                } while (mask);                                                \
            }                                                                  \
            loadB(((T) + 4) & (TILES - 1), SLOT);                              \
        }
        for (int t = 0; t < TILES; t += 4) {
            S2BODY(s0, t + 0)
            S2BODY(s1, t + 1)
            S2BODY(s2, t + 2)
            S2BODY(s3, t + 3)
        }
#undef S2BODY
    }
    __syncthreads();

    // ---- exact fp32 rescore: 4 lanes per candidate (coalesced 256B) ----
    unsigned cnt = lcnt; if (cnt > LISTCAP) cnt = LISTCAP;
    for (unsigned t4 = tid; t4 < cnt * 4; t4 += 256) {
        unsigned t = t4 >> 2; int q = t4 & 3;
        unsigned e = list[t];
        int row = (int)(e >> 12), c = (int)(e & 4095u);
        const float4* xp = reinterpret_cast<const float4*>(enc + (size_t)(pbase + row) * CDIM) + q * 4;
        const float4* ep = reinterpret_cast<const float4*>(cbf + (size_t)c * CDIM) + q * 4;
        float a0 = 0.f, a1 = 0.f, a2 = 0.f, a3 = 0.f;
#pragma unroll
        for (int i = 0; i < 4; ++i) {
            float4 xv = xp[i], ev = ep[i];
            a0 = fmaf(xv.x, ev.x, a0); a1 = fmaf(xv.y, ev.y, a1);
            a2 = fmaf(xv.z, ev.z, a2); a3 = fmaf(xv.w, ev.w, a3);
        }
        float p = (a0 + a1) + (a2 + a3);
        p += __shfl_xor(p, 1, 64);
        p += __shfl_xor(p, 2, 64);               // full dot in all 4 lanes
        if (q == 0) {
            float d2 = fmaf(-2.f, p, 2.f * h[c]);     // esq - 2*dot (bit-identical everywhere)
            unsigned bb = __float_as_uint(d2);
            unsigned ord = bb ^ (unsigned)(((int)bb >> 31) | 0x80000000);  // monotonic
            atomicMin(&mkey[row], ((unsigned long long)ord << 32) | (unsigned)c);
        }
    }
    __syncthreads();

    // ---- finalize: gather winner rows (4 threads per point) + idx ----
    {
        int p = tid >> 2, q = tid & 3;
        int c = (int)(mkey[p] & 4095u);
        const float4* ep = reinterpret_cast<const float4*>(cbf + (size_t)c * CDIM) + q * 4;
        float4* op = reinterpret_cast<float4*>(out + (size_t)(pbase + p) * CDIM) + q * 4;
#pragma unroll
        for (int i = 0; i < 4; ++i) op[i] = ep[i];
        if (tid < 64)
            out[(size_t)NPTS * CDIM + pbase + tid] = (float)(mkey[tid] & 4095u);
    }
}

extern "C" void kernel_launch(void* const* d_in, const int* in_sizes, int n_in,
                              void* d_out, int out_size, void* d_ws, size_t ws_size,
                              hipStream_t stream) {
    const float* enc = (const float*)d_in[0];
    const float* cb  = (const float*)d_in[1];
    float* out = (float*)d_out;

    // ws: cbb bf16[4096*64] (512KB) | h fp32[4096] (16KB)
    short* cbb = (short*)d_ws;
    float* hws = (float*)(cbb + (size_t)KCODES * CDIM);

    vq_prep<<<KCODES / 256, 256, 0, stream>>>(cb, cbb, hws);
    vq_main<<<NPTS / 64, 256, 0, stream>>>(enc, cb, cbb, hws, out);
}

// Round 16
// 134.003 us; speedup vs baseline: 1.4370x; 1.0100x over previous
//
#include <hip/hip_runtime.h>

// VQ-VAE quantization, round 16: bf16 MFMA prefilter + exact fp32 rescore.
// r15 base (135us) minus more per-body instructions:
//  - MFMA C-in = persistent mthr regs (C need not alias D) -> the 16 per-tile
//    acc-init ops disappear; acc_final = dot - thr; push test acc >= h (VGPR cmp)
//  - cbb/h padded by 4 tiles -> affine prefetch (no wrap select) -> compiler
//    strength-reduces addresses to pointer increments
// Sampled threshold (8/64 tiles/wave + cross-wave max) - DELTA=0.25 (>= 2x
// worst bf16 dot err) provably keeps the true winner; exact fp32 rescore +
// LDS atomicMin((ordbits(dist)<<32)|code) -> exact argmin, first-index ties.

#define NPTS    65536
#define CDIM    64
#define KCODES  4096
#define WAVES   4
#define KPW     (KCODES / WAVES)   // 1024 codes per wave
#define TILES   (KPW / 16)         // 64 tiles of 16 codes
#define PADC    64                 // 4 pad tiles (prefetch overrun target)
#define LISTCAP 8192
#define DELTA   0.25f

typedef __attribute__((ext_vector_type(8))) short short8;
typedef __attribute__((ext_vector_type(4))) float f32x4;

__device__ __forceinline__ unsigned short f2bf(float x) {
    unsigned u = __float_as_uint(x);
    return (unsigned short)((u + 0x7FFFu + ((u >> 16) & 1u)) >> 16);  // RNE
}

struct BT { short8 b0, b1; float hh; };

// cb fp32 -> bf16 copy + h[k] = 0.5*||e_k||^2
__global__ __launch_bounds__(256) void vq_prep(const float* __restrict__ cb,
                                               short* __restrict__ cbb,
                                               float* __restrict__ h) {
    int k = blockIdx.x * 256 + threadIdx.x;
    const float4* p = reinterpret_cast<const float4*>(cb + (size_t)k * CDIM);
    float s0 = 0.f, s1 = 0.f, s2 = 0.f, s3 = 0.f;
#pragma unroll
    for (int i = 0; i < 16; i += 2) {
        float4 va = p[i], vb = p[i + 1];
        s0 = fmaf(va.x, va.x, s0); s1 = fmaf(va.y, va.y, s1);
        s2 = fmaf(va.z, va.z, s2); s3 = fmaf(va.w, va.w, s3);
        s0 = fmaf(vb.x, vb.x, s0); s1 = fmaf(vb.y, vb.y, s1);
        s2 = fmaf(vb.z, vb.z, s2); s3 = fmaf(vb.w, vb.w, s3);
        short8 o;
        o[0] = (short)f2bf(va.x); o[1] = (short)f2bf(va.y);
        o[2] = (short)f2bf(va.z); o[3] = (short)f2bf(va.w);
        o[4] = (short)f2bf(vb.x); o[5] = (short)f2bf(vb.y);
        o[6] = (short)f2bf(vb.z); o[7] = (short)f2bf(vb.w);
        *reinterpret_cast<short8*>(cbb + (size_t)k * CDIM + i * 4) = o;
    }
    h[k] = 0.5f * ((s0 + s1) + (s2 + s3));
}

__global__ __launch_bounds__(256) void vq_main(const float* __restrict__ enc,
                                               const float* __restrict__ cbf,
                                               const short* __restrict__ cbb,
                                               const float* __restrict__ h,
                                               float* __restrict__ out) {
    __shared__ unsigned list[LISTCAP];
    __shared__ float rowmax[WAVES][64];
    __shared__ float thrL[64];
    __shared__ unsigned long long mkey[64];
    __shared__ unsigned lcnt;

    const int tid  = threadIdx.x;
    const int wid  = tid >> 6, lane = tid & 63;
    const int lrow = lane & 15, lseg = lane >> 4;
    const int pbase = blockIdx.x * 64;     // 64 points per block
    const int k0 = wid * KPW;              // this wave's 1024-code slice

    if (tid == 0) lcnt = 0;
    if (tid < 64) mkey[tid] = ~0ull;

    // ---- A fragments: the block's 64 points as bf16 ----
    // 16x16x32 A layout: row = lane&15, k = (lane>>4)*8 + e (+32 per kk)
    short8 afr[4][2];
#pragma unroll
    for (int rt = 0; rt < 4; ++rt)
#pragma unroll
        for (int kk = 0; kk < 2; ++kk) {
            const float4* xp = reinterpret_cast<const float4*>(
                enc + (size_t)(pbase + rt * 16 + lrow) * CDIM + kk * 32 + lseg * 8);
            float4 v0 = xp[0], v1 = xp[1];
            short8 a;
            a[0] = (short)f2bf(v0.x); a[1] = (short)f2bf(v0.y);
            a[2] = (short)f2bf(v0.z); a[3] = (short)f2bf(v0.w);
            a[4] = (short)f2bf(v1.x); a[5] = (short)f2bf(v1.y);
            a[6] = (short)f2bf(v1.z); a[7] = (short)f2bf(v1.w);
            afr[rt][kk] = a;
        }
    __syncthreads();   // lcnt/mkey init visible before any push

    auto loadB = [&](int ct, BT& s) {
        int code = k0 + ct * 16 + lrow;    // may run PADC past KCODES (pad-backed)
        const short* base = cbb + (size_t)code * CDIM + lseg * 8;
        s.b0 = *reinterpret_cast<const short8*>(base);
        s.b1 = *reinterpret_cast<const short8*>(base + 32);
        s.hh = h[code];
    };

    // ---- sample sweep: tiles {0,8,...,56}, row max only ----
    f32x4 best[4];
#pragma unroll
    for (int rt = 0; rt < 4; ++rt)
#pragma unroll
        for (int i = 0; i < 4; ++i) best[rt][i] = -__builtin_inff();

    {
        BT s0, s1, s2, s3;
        loadB(0, s0); loadB(8, s1); loadB(16, s2); loadB(24, s3);
#define SSBODY(SLOT, J)                                                        \
        {                                                                      \
            float nh = -SLOT.hh;                                               \
            f32x4 acc[4];                                                      \
            _Pragma("unroll")                                                  \
            for (int rt = 0; rt < 4; ++rt) {                                   \
                acc[rt][0] = nh; acc[rt][1] = nh;                              \
                acc[rt][2] = nh; acc[rt][3] = nh;                              \
            }                                                                  \
            _Pragma("unroll")                                                  \
            for (int rt = 0; rt < 4; ++rt)                                     \
                acc[rt] = __builtin_amdgcn_mfma_f32_16x16x32_bf16(afr[rt][0], SLOT.b0, acc[rt], 0, 0, 0); \
            _Pragma("unroll")                                                  \
            for (int rt = 0; rt < 4; ++rt)                                     \
                acc[rt] = __builtin_amdgcn_mfma_f32_16x16x32_bf16(afr[rt][1], SLOT.b1, acc[rt], 0, 0, 0); \
            _Pragma("unroll")                                                  \
            for (int rt = 0; rt < 4; ++rt)                                     \
                _Pragma("unroll")                                              \
                for (int i = 0; i < 4; ++i)                                    \
                    best[rt][i] = fmaxf(best[rt][i], acc[rt][i]);              \
            loadB((((J) + 4) & 7) * 8, SLOT);                                  \
        }
        SSBODY(s0, 0) SSBODY(s1, 1) SSBODY(s2, 2) SSBODY(s3, 3)
        SSBODY(s0, 4) SSBODY(s1, 5) SSBODY(s2, 6) SSBODY(s3, 7)
#undef SSBODY
    }

    // intra-wave max over the 16 col-lanes
#pragma unroll
    for (int m = 1; m <= 8; m <<= 1)
#pragma unroll
        for (int rt = 0; rt < 4; ++rt)
#pragma unroll
            for (int i = 0; i < 4; ++i)
                best[rt][i] = fmaxf(best[rt][i], __shfl_xor(best[rt][i], m, 64));
    if (lrow == 0) {   // lanes 0,16,32,48 cover all 64 rows
#pragma unroll
        for (int rt = 0; rt < 4; ++rt)
#pragma unroll
            for (int i = 0; i < 4; ++i)
                rowmax[wid][rt * 16 + lseg * 4 + i] = best[rt][i];
    }
    __syncthreads();
    if (tid < 64) {    // cross-wave max of sampled maxes -> threshold
        float m0 = fmaxf(rowmax[0][tid], rowmax[1][tid]);
        float m1 = fmaxf(rowmax[2][tid], rowmax[3][tid]);
        thrL[tid] = fmaxf(m0, m1) - DELTA;
    }
    __syncthreads();

    // mthr = -thr, persistent MFMA C-in for the whole sweep
    f32x4 mthr[4];
#pragma unroll
    for (int rt = 0; rt < 4; ++rt)
#pragma unroll
        for (int i = 0; i < 4; ++i) mthr[rt][i] = -thrL[rt * 16 + lseg * 4 + i];

    // ---- sweep 2: C-in = mthr (no per-tile init); test acc >= h; ctz push ----
    {
        BT s0, s1, s2, s3;
        loadB(0, s0); loadB(1, s1); loadB(2, s2); loadB(3, s3);
#define S2BODY(SLOT, T)                                                        \
        {                                                                      \
            f32x4 acc[4];                                                      \
            _Pragma("unroll")                                                  \
            for (int rt = 0; rt < 4; ++rt)                                     \
                acc[rt] = __builtin_amdgcn_mfma_f32_16x16x32_bf16(afr[rt][0], SLOT.b0, mthr[rt], 0, 0, 0); \
            _Pragma("unroll")                                                  \
            for (int rt = 0; rt < 4; ++rt)                                     \
                acc[rt] = __builtin_amdgcn_mfma_f32_16x16x32_bf16(afr[rt][1], SLOT.b1, acc[rt], 0, 0, 0); \
            float hh = SLOT.hh;                                                \
            unsigned mask = 0u;                                                \
            _Pragma("unroll")                                                  \
            for (int rt = 0; rt < 4; ++rt)                                     \
                _Pragma("unroll")                                              \
                for (int i = 0; i < 4; ++i)                                    \
                    mask |= (acc[rt][i] >= hh) ? (1u << (rt * 4 + i)) : 0u;    \
            if (mask) {                                                        \
                unsigned code = (unsigned)(k0 + (T) * 16 + lrow);              \
                do {                                                           \
                    int kz = __builtin_ctz(mask);                              \
                    mask &= mask - 1u;                                         \
                    unsigned row = ((unsigned)(kz >> 2) << 4)                  \
                                 + (unsigned)(lseg * 4) + (unsigned)(kz & 3);  /* C/D map (m89) */ \
                    unsigned pos = atomicAdd(&lcnt, 1u);                       \
                    if (pos < LISTCAP) list[pos] = (row << 12) | code;         \
                } while (mask);                                                \
            }                                                                  \
            loadB((T) + 4, SLOT);   /* affine; pad-backed past TILES */        \
        }
        for (int t = 0; t < TILES; t += 4) {
            S2BODY(s0, t + 0)
            S2BODY(s1, t + 1)
            S2BODY(s2, t + 2)
            S2BODY(s3, t + 3)
        }
#undef S2BODY
    }
    __syncthreads();

    // ---- exact fp32 rescore: 4 lanes per candidate (coalesced 256B) ----
    unsigned cnt = lcnt; if (cnt > LISTCAP) cnt = LISTCAP;
    for (unsigned t4 = tid; t4 < cnt * 4; t4 += 256) {
        unsigned t = t4 >> 2; int q = t4 & 3;
        unsigned e = list[t];
        int row = (int)(e >> 12), c = (int)(e & 4095u);
        const float4* xp = reinterpret_cast<const float4*>(enc + (size_t)(pbase + row) * CDIM) + q * 4;
        const float4* ep = reinterpret_cast<const float4*>(cbf + (size_t)c * CDIM) + q * 4;
        float a0 = 0.f, a1 = 0.f, a2 = 0.f, a3 = 0.f;
#pragma unroll
        for (int i = 0; i < 4; ++i) {
            float4 xv = xp[i], ev = ep[i];
            a0 = fmaf(xv.x, ev.x, a0); a1 = fmaf(xv.y, ev.y, a1);
            a2 = fmaf(xv.z, ev.z, a2); a3 = fmaf(xv.w, ev.w, a3);
        }
        float p = (a0 + a1) + (a2 + a3);
        p += __shfl_xor(p, 1, 64);
        p += __shfl_xor(p, 2, 64);               // full dot in all 4 lanes
        if (q == 0) {
            float d2 = fmaf(-2.f, p, 2.f * h[c]);     // esq - 2*dot (bit-identical everywhere)
            unsigned bb = __float_as_uint(d2);
            unsigned ord = bb ^ (unsigned)(((int)bb >> 31) | 0x80000000);  // monotonic
            atomicMin(&mkey[row], ((unsigned long long)ord << 32) | (unsigned)c);
        }
    }
    __syncthreads();

    // ---- finalize: gather winner rows (4 threads per point) + idx ----
    {
        int p = tid >> 2, q = tid & 3;
        int c = (int)(mkey[p] & 4095u);
        const float4* ep = reinterpret_cast<const float4*>(cbf + (size_t)c * CDIM) + q * 4;
        float4* op = reinterpret_cast<float4*>(out + (size_t)(pbase + p) * CDIM) + q * 4;
#pragma unroll
        for (int i = 0; i < 4; ++i) op[i] = ep[i];
        if (tid < 64)
            out[(size_t)NPTS * CDIM + pbase + tid] = (float)(mkey[tid] & 4095u);
    }
}

extern "C" void kernel_launch(void* const* d_in, const int* in_sizes, int n_in,
                              void* d_out, int out_size, void* d_ws, size_t ws_size,
                              hipStream_t stream) {
    const float* enc = (const float*)d_in[0];
    const float* cb  = (const float*)d_in[1];
    float* out = (float*)d_out;

    // ws: cbb bf16[(4096+64)*64] (520KB) | h fp32[4096+64] (16.25KB)
    short* cbb = (short*)d_ws;
    float* hws = (float*)(cbb + (size_t)(KCODES + PADC) * CDIM);

    vq_prep<<<KCODES / 256, 256, 0, stream>>>(cb, cbb, hws);
    vq_main<<<NPTS / 64, 256, 0, stream>>>(enc, cb, cbb, hws, out);
}